// Round 5
// baseline (4733.913 us; speedup 1.0000x reference)
//
#include <hip/hip_runtime.h>
#include <hip/hip_bf16.h>
#include <math.h>

#define BATCH   1024
#define SEQ     80
#define EMB     512
#define UNITS   512
#define ROWS    16
#define NBLK    (BATCH / ROWS)   // 64 persistent blocks, no inter-block comms
#define THREADS 1024             // 16 waves = 4/SIMD; wave w owns cols [w*32, w*32+32)
#define REG     8192             // LDS region size in ushorts (16 rows x 512)

typedef __attribute__((ext_vector_type(8))) short          bf16x8;
typedef __attribute__((ext_vector_type(8))) unsigned short u16x8;
typedef __attribute__((ext_vector_type(4))) float          f32x4;

__device__ inline unsigned short f2bf(float f) {
    __hip_bfloat16 h = __float2bfloat16(f);
    return *reinterpret_cast<unsigned short*>(&h);
}
__device__ inline float bf2f(unsigned short u) {
    unsigned int x = ((unsigned int)u) << 16;
    return __uint_as_float(x);
}
__device__ inline float tanh_fast(float x) {
    float e = __expf(2.f * x);
    return 1.f - 2.f / (e + 1.f);
}

// ---------------------------------------------------------------------------
// Pack weights into MFMA B-fragment slabs, bf16.
// slab s = ((p*16 + w)*2 + i)*32 + k0 ; elem = s*512 + lane*8 + j
// value = Wp[k0*32 + (lane>>4)*8 + j][w*32 + i*16 + (lane&15)]
// Wp = [Wx ; Wh] stacked (K=1024). 2048 slabs = 2 MB, stays L2-resident.
// ---------------------------------------------------------------------------
__global__ __launch_bounds__(256) void pack_weights(
    const float* __restrict__ W0x, const float* __restrict__ W0h,
    const float* __restrict__ W1x, const float* __restrict__ W1h,
    unsigned short* __restrict__ wpack)
{
    int g    = blockIdx.x * 4 + (threadIdx.x >> 6);   // 0..2047
    int lane = threadIdx.x & 63;
    int p    = g >> 10;
    int rem  = g & 1023;
    int w    = rem >> 6;
    int i    = (rem >> 5) & 1;
    int k0   = rem & 31;
    int n    = w * 32 + i * 16 + (lane & 15);
    int kb   = k0 * 32 + (lane >> 4) * 8;
    const float* Wx = p ? W1x : W0x;
    const float* Wh = p ? W1h : W0h;

    u16x8 v;
#pragma unroll
    for (int j = 0; j < 8; ++j) {
        int k = kb + j;
        float f = (k < 512) ? Wx[(size_t)k * UNITS + n]
                            : Wh[(size_t)(k - 512) * UNITS + n];
        v[j] = f2bf(f);
    }
    *(u16x8*)(wpack + (size_t)g * 512 + lane * 8) = v;
}

// 16-k0 half-phase: 2 col-tiles, depth-4 B prefetch, A from LDS region.
// wb points at (phase, wave, tile0, k0=first) slab + lane*8; tile1 = +16384.
__device__ __forceinline__ void runp(
    f32x4& acc0, f32x4& acc1,
    const unsigned short* __restrict__ wb,
    const unsigned short* __restrict__ areg,   // LDS region base
    int l15, int quad, int sw8)
{
    bf16x8 Bf[4][2];
#pragma unroll
    for (int d = 0; d < 4; ++d) {
        Bf[d][0] = *(const bf16x8*)(wb + (size_t)d * 512);
        Bf[d][1] = *(const bf16x8*)(wb + (size_t)d * 512 + 16384);
    }
#pragma unroll
    for (int k = 0; k < 16; ++k) {
        bf16x8 a = *(const bf16x8*)(areg + l15 * 512 +
                                    (((k * 4 + quad) ^ sw8) * 8));
        bf16x8 b0 = Bf[k & 3][0], b1 = Bf[k & 3][1];
        if (k + 4 < 16) {
            Bf[k & 3][0] = *(const bf16x8*)(wb + (size_t)(k + 4) * 512);
            Bf[k & 3][1] = *(const bf16x8*)(wb + (size_t)(k + 4) * 512 + 16384);
        }
        acc0 = __builtin_amdgcn_mfma_f32_16x16x32_bf16(a, b0, acc0, 0, 0, 0);
        acc1 = __builtin_amdgcn_mfma_f32_16x16x32_bf16(a, b1, acc1, 0, 0, 0);
    }
}

// ---------------------------------------------------------------------------
// 64 self-contained blocks x 16 rows x 512 cols. LDS 64 KB:
//   R0 = x(t), R1/R2 = h0 double-buffer, R3 = h1 (in-place, extra barrier).
// All regions 16x512 bf16, 16B granules XOR-swizzled by (row&7).
// Step: ph1 = [x|h0_r]@W0 -> h0_w | B1 | ph2 = [h0_w|h1]@W1 | Bx |
//       write h1 + x(t+1) | B2.   3 barriers, zero global sync.
// ---------------------------------------------------------------------------
__global__ __launch_bounds__(THREADS, 4) void rnn_local_kernel(
    const int*   __restrict__ inputs,
    const float* __restrict__ emb,
    const float* __restrict__ b0,
    const float* __restrict__ b1,
    const unsigned short* __restrict__ wpack,
    const float* __restrict__ Wout,
    const float* __restrict__ bout,
    float*       __restrict__ out)
{
    __shared__ unsigned short hcat[4 * REG];   // 65536 B

    const int tid   = threadIdx.x;
    const int w     = tid >> 6;        // wave 0..15
    const int lane  = tid & 63;
    const int quad  = lane >> 4;
    const int l15   = lane & 15;
    const int sw8   = l15 & 7;
    const int rbase = blockIdx.x * ROWS;

    // zero h regions R1..R3
    for (int i = tid; i < 3 * REG; i += THREADS)
        hcat[REG + i] = 0;

    // x staging: wave w handles row w; lane handles granule c8 = lane
    const int xr = w;
    const int xc8 = lane;

    // stage x_0 into R0
    {
        int idx = inputs[(rbase + xr) * SEQ + 0];
        const float* ep = emb + (size_t)idx * EMB + xc8 * 8;
        float4 fa = *(const float4*)(ep);
        float4 fb = *(const float4*)(ep + 4);
        u16x8 v;
        v[0]=f2bf(fa.x); v[1]=f2bf(fa.y); v[2]=f2bf(fa.z); v[3]=f2bf(fa.w);
        v[4]=f2bf(fb.x); v[5]=f2bf(fb.y); v[6]=f2bf(fb.z); v[7]=f2bf(fb.w);
        *(u16x8*)(hcat + xr * 512 + ((xc8 ^ (xr & 7)) * 8)) = v;
    }
    __syncthreads();

    const int   col0  = w * 32 + l15;          // tile 0 column
    const float bias0_0 = b0[col0], bias0_1 = b0[col0 + 16];
    const float bias1_0 = b1[col0], bias1_1 = b1[col0 + 16];

    // per-wave packed-weight bases (+ lane*8)
    const unsigned short* wb0 = wpack + (size_t)w * 64 * 512 + lane * 8;
    const unsigned short* wb1 = wb0 + (size_t)1024 * 512;

    // C-layout store helper indices: row = quad*4 + j, col = w*32 + i*16 + l15
    const int c8t0 = w * 4 + (l15 >> 3);       // granule of tile0 col
    const int cit  = l15 & 7;                  // within-granule index

    for (int t = 0; t < SEQ; ++t) {
        const unsigned short* h0r = hcat + REG * (1 + (t & 1));
        unsigned short*       h0w = hcat + REG * (1 + ((t + 1) & 1));
        unsigned short*       h1  = hcat + REG * 3;

        // ---- phase 1: pre0 = [x | h0_r] @ W0 + b0 ----
        f32x4 acc0 = {bias0_0, bias0_0, bias0_0, bias0_0};
        f32x4 acc1 = {bias0_1, bias0_1, bias0_1, bias0_1};
        runp(acc0, acc1, wb0, hcat, l15, quad, sw8);              // Wx, A=x
        runp(acc0, acc1, wb0 + (size_t)16 * 512, h0r, l15, quad, sw8); // Wh, A=h0

        // write h0' into h0w (other buffer; readers of h0r unaffected)
#pragma unroll
        for (int j = 0; j < 4; ++j) {
            int row = quad * 4 + j;
            int s   = (row & 7);
            h0w[row * 512 + ((c8t0 ^ s) * 8) + cit]       = f2bf(tanh_fast(acc0[j]));
            h0w[row * 512 + (((c8t0 + 2) ^ s) * 8) + cit] = f2bf(tanh_fast(acc1[j]));
        }
        __syncthreads();                                           // B1

        // issue x(t+1) prefetch (drains during phase 2)
        int tn  = (t + 1 < SEQ) ? t + 1 : t;
        int idx = inputs[(rbase + xr) * SEQ + tn];
        const float* ep = emb + (size_t)idx * EMB + xc8 * 8;
        float4 fa = *(const float4*)(ep);
        float4 fb = *(const float4*)(ep + 4);

        // ---- phase 2: pre1 = [h0' | h1] @ W1 + b1 ----
        f32x4 acc2 = {bias1_0, bias1_0, bias1_0, bias1_0};
        f32x4 acc3 = {bias1_1, bias1_1, bias1_1, bias1_1};
        runp(acc2, acc3, wb1, h0w, l15, quad, sw8);               // W1x, A=h0'
        runp(acc2, acc3, wb1 + (size_t)16 * 512, h1, l15, quad, sw8); // W1h, A=h1
        __syncthreads();                     // Bx: all ph2 reads of h1,h0' done

        // write h1' in place; stage x(t+1)
#pragma unroll
        for (int j = 0; j < 4; ++j) {
            int row = quad * 4 + j;
            int s   = (row & 7);
            h1[row * 512 + ((c8t0 ^ s) * 8) + cit]       = f2bf(tanh_fast(acc2[j]));
            h1[row * 512 + (((c8t0 + 2) ^ s) * 8) + cit] = f2bf(tanh_fast(acc3[j]));
        }
        {
            u16x8 v;
            v[0]=f2bf(fa.x); v[1]=f2bf(fa.y); v[2]=f2bf(fa.z); v[3]=f2bf(fa.w);
            v[4]=f2bf(fb.x); v[5]=f2bf(fb.y); v[6]=f2bf(fb.z); v[7]=f2bf(fb.w);
            *(u16x8*)(hcat + xr * 512 + ((xc8 ^ (xr & 7)) * 8)) = v;
        }
        __syncthreads();                                           // B2
    }

    // ---- epilogue: out = sigmoid(h1 @ Wout + bout); wave w does row w ----
    {
        const unsigned short* h1 = hcat + REG * 3;
        int r = w;
        float s = 0.f;
#pragma unroll
        for (int j = 0; j < 8; ++j) {
            int c  = lane + 64 * j;
            int c8 = c >> 3, ci = c & 7;
            s += bf2f(h1[r * 512 + ((c8 ^ (r & 7)) * 8) + ci]) * Wout[c];
        }
#pragma unroll
        for (int off = 32; off > 0; off >>= 1) s += __shfl_down(s, off);
        if (lane == 0) {
            float z = s + bout[0];
            out[rbase + r] = 1.f / (1.f + __expf(-z));
        }
    }
}

extern "C" void kernel_launch(void* const* d_in, const int* in_sizes, int n_in,
                              void* d_out, int out_size, void* d_ws, size_t ws_size,
                              hipStream_t stream) {
    const int*   inputs = (const int*)d_in[0];
    const float* emb    = (const float*)d_in[1];
    const float* W0x    = (const float*)d_in[2];
    const float* W0h    = (const float*)d_in[3];
    const float* b0     = (const float*)d_in[4];
    const float* W1x    = (const float*)d_in[5];
    const float* W1h    = (const float*)d_in[6];
    const float* b1     = (const float*)d_in[7];
    const float* Wout   = (const float*)d_in[8];
    const float* bout   = (const float*)d_in[9];
    float*       out    = (float*)d_out;

    unsigned short* wpack = (unsigned short*)d_ws;   // 2 MB packed bf16 weights

    pack_weights<<<512, 256, 0, stream>>>(W0x, W0h, W1x, W1h, wpack);
    rnn_local_kernel<<<NBLK, THREADS, 0, stream>>>(
        inputs, emb, b0, b1, wpack, Wout, bout, out);
}

// Round 6
// 4727.073 us; speedup vs baseline: 1.0014x; 1.0014x over previous
//
#include <hip/hip_runtime.h>
#include <hip/hip_bf16.h>
#include <math.h>

#define BATCH   1024
#define SEQ     80
#define EMB     512
#define UNITS   512
#define ROWS    16
#define NBLK    (BATCH / ROWS)   // 64 persistent blocks, no inter-block comms
#define THREADS 1024             // 16 waves = 4/SIMD; wave w owns cols [w*32, w*32+32)
#define REG     8192             // LDS region size in ushorts (16 rows x 512)

typedef __attribute__((ext_vector_type(8))) short          bf16x8;
typedef __attribute__((ext_vector_type(8))) unsigned short u16x8;
typedef __attribute__((ext_vector_type(4))) float          f32x4;

__device__ inline unsigned short f2bf(float f) {
    __hip_bfloat16 h = __float2bfloat16(f);
    return *reinterpret_cast<unsigned short*>(&h);
}
__device__ inline float bf2f(unsigned short u) {
    unsigned int x = ((unsigned int)u) << 16;
    return __uint_as_float(x);
}
__device__ inline float tanh_fast(float x) {
    float e = __expf(2.f * x);
    return 1.f - 2.f / (e + 1.f);
}

// ---------------------------------------------------------------------------
// Pack weights into MFMA B-fragment slabs, bf16.
// slab s = ((p*16 + w)*2 + i)*32 + k0 ; elem = s*512 + lane*8 + j
// value = Wp[k0*32 + (lane>>4)*8 + j][w*32 + i*16 + (lane&15)]
// Wp = [Wx ; Wh] stacked (K=1024). 2048 slabs = 2 MB, stays L2-resident.
// ---------------------------------------------------------------------------
__global__ __launch_bounds__(256) void pack_weights(
    const float* __restrict__ W0x, const float* __restrict__ W0h,
    const float* __restrict__ W1x, const float* __restrict__ W1h,
    unsigned short* __restrict__ wpack)
{
    int g    = blockIdx.x * 4 + (threadIdx.x >> 6);   // 0..2047
    int lane = threadIdx.x & 63;
    int p    = g >> 10;
    int rem  = g & 1023;
    int w    = rem >> 6;
    int i    = (rem >> 5) & 1;
    int k0   = rem & 31;
    int n    = w * 32 + i * 16 + (lane & 15);
    int kb   = k0 * 32 + (lane >> 4) * 8;
    const float* Wx = p ? W1x : W0x;
    const float* Wh = p ? W1h : W0h;

    u16x8 v;
#pragma unroll
    for (int j = 0; j < 8; ++j) {
        int k = kb + j;
        float f = (k < 512) ? Wx[(size_t)k * UNITS + n]
                            : Wh[(size_t)(k - 512) * UNITS + n];
        v[j] = f2bf(f);
    }
    *(u16x8*)(wpack + (size_t)g * 512 + lane * 8) = v;
}

// 16-k0 half-phase: 2 col-tiles, depth-4 B prefetch, A from LDS region.
// wb points at (phase, wave, tile0, k0=first) slab + lane*8; tile1 = +16384.
__device__ __forceinline__ void runp(
    f32x4& acc0, f32x4& acc1,
    const unsigned short* __restrict__ wb,
    const unsigned short* __restrict__ areg,   // LDS region base
    int l15, int quad, int sw8)
{
    bf16x8 Bf[4][2];
#pragma unroll
    for (int d = 0; d < 4; ++d) {
        Bf[d][0] = *(const bf16x8*)(wb + (size_t)d * 512);
        Bf[d][1] = *(const bf16x8*)(wb + (size_t)d * 512 + 16384);
    }
#pragma unroll
    for (int k = 0; k < 16; ++k) {
        bf16x8 a = *(const bf16x8*)(areg + l15 * 512 +
                                    (((k * 4 + quad) ^ sw8) * 8));
        bf16x8 b0 = Bf[k & 3][0], b1 = Bf[k & 3][1];
        if (k + 4 < 16) {
            Bf[k & 3][0] = *(const bf16x8*)(wb + (size_t)(k + 4) * 512);
            Bf[k & 3][1] = *(const bf16x8*)(wb + (size_t)(k + 4) * 512 + 16384);
        }
        acc0 = __builtin_amdgcn_mfma_f32_16x16x32_bf16(a, b0, acc0, 0, 0, 0);
        acc1 = __builtin_amdgcn_mfma_f32_16x16x32_bf16(a, b1, acc1, 0, 0, 0);
    }
}

// ---------------------------------------------------------------------------
// 64 self-contained blocks x 16 rows x 512 cols. LDS 64 KB:
//   R0 = x(t), R1/R2 = h0 double-buffer, R3 = h1 (in-place, extra barrier).
// All regions 16x512 bf16, 16B granules XOR-swizzled by (row&7).
// Step: ph1 = [x|h0_r]@W0 -> h0_w | B1 | ph2 = [h0_w|h1]@W1 | Bx |
//       write h1 + x(t+1) | B2.   3 barriers, zero global sync.
// NOTE: __launch_bounds__ has NO min-waves arg — round 5's (1024,4) clamped
// VGPRs to 64 and spilled the B-prefetch buffers to scratch (5 GB FETCH).
// ---------------------------------------------------------------------------
__global__ __launch_bounds__(THREADS) void rnn_local_kernel(
    const int*   __restrict__ inputs,
    const float* __restrict__ emb,
    const float* __restrict__ b0,
    const float* __restrict__ b1,
    const unsigned short* __restrict__ wpack,
    const float* __restrict__ Wout,
    const float* __restrict__ bout,
    float*       __restrict__ out)
{
    __shared__ unsigned short hcat[4 * REG];   // 65536 B

    const int tid   = threadIdx.x;
    const int w     = tid >> 6;        // wave 0..15
    const int lane  = tid & 63;
    const int quad  = lane >> 4;
    const int l15   = lane & 15;
    const int sw8   = l15 & 7;
    const int rbase = blockIdx.x * ROWS;

    // zero h regions R1..R3
    for (int i = tid; i < 3 * REG; i += THREADS)
        hcat[REG + i] = 0;

    // x staging: wave w handles row w; lane handles granule c8 = lane
    const int xr = w;
    const int xc8 = lane;

    // stage x_0 into R0
    {
        int idx = inputs[(rbase + xr) * SEQ + 0];
        const float* ep = emb + (size_t)idx * EMB + xc8 * 8;
        float4 fa = *(const float4*)(ep);
        float4 fb = *(const float4*)(ep + 4);
        u16x8 v;
        v[0]=f2bf(fa.x); v[1]=f2bf(fa.y); v[2]=f2bf(fa.z); v[3]=f2bf(fa.w);
        v[4]=f2bf(fb.x); v[5]=f2bf(fb.y); v[6]=f2bf(fb.z); v[7]=f2bf(fb.w);
        *(u16x8*)(hcat + xr * 512 + ((xc8 ^ (xr & 7)) * 8)) = v;
    }
    __syncthreads();

    const int   col0  = w * 32 + l15;          // tile 0 column
    const float bias0_0 = b0[col0], bias0_1 = b0[col0 + 16];
    const float bias1_0 = b1[col0], bias1_1 = b1[col0 + 16];

    // per-wave packed-weight bases (+ lane*8)
    const unsigned short* wb0 = wpack + (size_t)w * 64 * 512 + lane * 8;
    const unsigned short* wb1 = wb0 + (size_t)1024 * 512;

    // C-layout store helper indices: row = quad*4 + j, col = w*32 + i*16 + l15
    const int c8t0 = w * 4 + (l15 >> 3);       // granule of tile0 col
    const int cit  = l15 & 7;                  // within-granule index

    for (int t = 0; t < SEQ; ++t) {
        const unsigned short* h0r = hcat + REG * (1 + (t & 1));
        unsigned short*       h0w = hcat + REG * (1 + ((t + 1) & 1));
        unsigned short*       h1  = hcat + REG * 3;

        // ---- phase 1: pre0 = [x | h0_r] @ W0 + b0 ----
        f32x4 acc0 = {bias0_0, bias0_0, bias0_0, bias0_0};
        f32x4 acc1 = {bias0_1, bias0_1, bias0_1, bias0_1};
        runp(acc0, acc1, wb0, hcat, l15, quad, sw8);              // Wx, A=x
        runp(acc0, acc1, wb0 + (size_t)16 * 512, h0r, l15, quad, sw8); // Wh, A=h0

        // write h0' into h0w (other buffer; readers of h0r unaffected)
#pragma unroll
        for (int j = 0; j < 4; ++j) {
            int row = quad * 4 + j;
            int s   = (row & 7);
            h0w[row * 512 + ((c8t0 ^ s) * 8) + cit]       = f2bf(tanh_fast(acc0[j]));
            h0w[row * 512 + (((c8t0 + 2) ^ s) * 8) + cit] = f2bf(tanh_fast(acc1[j]));
        }
        __syncthreads();                                           // B1

        // issue x(t+1) prefetch (drains during phase 2)
        int tn  = (t + 1 < SEQ) ? t + 1 : t;
        int idx = inputs[(rbase + xr) * SEQ + tn];
        const float* ep = emb + (size_t)idx * EMB + xc8 * 8;
        float4 fa = *(const float4*)(ep);
        float4 fb = *(const float4*)(ep + 4);

        // ---- phase 2: pre1 = [h0' | h1] @ W1 + b1 ----
        f32x4 acc2 = {bias1_0, bias1_0, bias1_0, bias1_0};
        f32x4 acc3 = {bias1_1, bias1_1, bias1_1, bias1_1};
        runp(acc2, acc3, wb1, h0w, l15, quad, sw8);               // W1x, A=h0'
        runp(acc2, acc3, wb1 + (size_t)16 * 512, h1, l15, quad, sw8); // W1h, A=h1
        __syncthreads();                     // Bx: all ph2 reads of h1,h0' done

        // write h1' in place; stage x(t+1)
#pragma unroll
        for (int j = 0; j < 4; ++j) {
            int row = quad * 4 + j;
            int s   = (row & 7);
            h1[row * 512 + ((c8t0 ^ s) * 8) + cit]       = f2bf(tanh_fast(acc2[j]));
            h1[row * 512 + (((c8t0 + 2) ^ s) * 8) + cit] = f2bf(tanh_fast(acc3[j]));
        }
        {
            u16x8 v;
            v[0]=f2bf(fa.x); v[1]=f2bf(fa.y); v[2]=f2bf(fa.z); v[3]=f2bf(fa.w);
            v[4]=f2bf(fb.x); v[5]=f2bf(fb.y); v[6]=f2bf(fb.z); v[7]=f2bf(fb.w);
            *(u16x8*)(hcat + xr * 512 + ((xc8 ^ (xr & 7)) * 8)) = v;
        }
        __syncthreads();                                           // B2
    }

    // ---- epilogue: out = sigmoid(h1 @ Wout + bout); wave w does row w ----
    {
        const unsigned short* h1 = hcat + REG * 3;
        int r = w;
        float s = 0.f;
#pragma unroll
        for (int j = 0; j < 8; ++j) {
            int c  = lane + 64 * j;
            int c8 = c >> 3, ci = c & 7;
            s += bf2f(h1[r * 512 + ((c8 ^ (r & 7)) * 8) + ci]) * Wout[c];
        }
#pragma unroll
        for (int off = 32; off > 0; off >>= 1) s += __shfl_down(s, off);
        if (lane == 0) {
            float z = s + bout[0];
            out[rbase + r] = 1.f / (1.f + __expf(-z));
        }
    }
}

extern "C" void kernel_launch(void* const* d_in, const int* in_sizes, int n_in,
                              void* d_out, int out_size, void* d_ws, size_t ws_size,
                              hipStream_t stream) {
    const int*   inputs = (const int*)d_in[0];
    const float* emb    = (const float*)d_in[1];
    const float* W0x    = (const float*)d_in[2];
    const float* W0h    = (const float*)d_in[3];
    const float* b0     = (const float*)d_in[4];
    const float* W1x    = (const float*)d_in[5];
    const float* W1h    = (const float*)d_in[6];
    const float* b1     = (const float*)d_in[7];
    const float* Wout   = (const float*)d_in[8];
    const float* bout   = (const float*)d_in[9];
    float*       out    = (float*)d_out;

    unsigned short* wpack = (unsigned short*)d_ws;   // 2 MB packed bf16 weights

    pack_weights<<<512, 256, 0, stream>>>(W0x, W0h, W1x, W1h, wpack);
    rnn_local_kernel<<<NBLK, THREADS, 0, stream>>>(
        inputs, emb, b0, b1, wpack, Wout, bout, out);
}